// Round 2
// baseline (4640.561 us; speedup 1.0000x reference)
//
#include <hip/hip_runtime.h>
#include <hip/hip_cooperative_groups.h>

namespace cg = cooperative_groups;

#define NN   4096
#define TT   17
#define NTOT (NN*TT)          // 69632
#define NBLK 256
#define NTHR 512
#define KSL  2048             // k-range per block (2 k-blocks)
#define RPB  32               // rows per block (128 row-blocks)
#define NITMAX 48

// ws layout (floats): r p s x wp0 wp1 [each NTOT], gam[48*17] del[48*17] ssq[17] rhs[17]

__global__ __launch_bounds__(NTHR)
void gp_cg_kernel(const float* __restrict__ Km, const float* __restrict__ yv,
                  const float* __restrict__ Zm, const float* __restrict__ noise,
                  const int* __restrict__ cg_iters, float* __restrict__ out,
                  float* __restrict__ ws)
{
    cg::grid_group grid = cg::this_grid();
    const int tid  = threadIdx.x;
    const int b    = blockIdx.x;
    const int lane = tid & 63;
    const int w    = tid >> 6;       // wave 0..7
    const int kb   = b >> 7;         // 0..1  k-block
    const int rb   = b & 127;        // 0..127 row-block

    float* r_  = ws;
    float* p_  = r_  + NTOT;
    float* s_  = p_  + NTOT;
    float* x_  = s_  + NTOT;
    float* wp0 = x_  + NTOT;
    float* wp1 = wp0 + NTOT;
    float* gam = wp1 + NTOT;         // [48][17]
    float* del = gam + NITMAX*TT;    // [48][17]
    float* ssq = del + NITMAX*TT;    // [17]
    float* rhs = ssq + TT;           // [17]

    const float sigma2 = noise[0]*noise[0];
    const int   niters = cg_iters[0];

    __shared__ float rl[TT*KSL];     // 136 KB r-slice, [c][k] layout (conflict-free)
    __shared__ float red[TT];        // per-col delta partial
    __shared__ float gred[TT];       // per-col gamma partial
    __shared__ float al_lds[TT], be_lds[TT], aprev[TT];

    // ---- S0: zero x,p,s and scalar region ----
    for (int i = b*NTHR + tid; i < NTOT; i += NBLK*NTHR) { x_[i]=0.f; p_[i]=0.f; s_[i]=0.f; }
    for (int i = b*NTHR + tid; i < 2*NITMAX*TT + 2*TT; i += NBLK*NTHR) gam[i] = 0.f;
    if (tid < TT) aprev[tid] = 1.f;
    grid.sync();

    // ---- S1: per-column sum of squares of [y | Z] ----
    if (tid < TT) red[tid] = 0.f;
    __syncthreads();
    if (tid < 16*TT) {
        int n = b*16 + tid/TT, c = tid % TT;
        float v = (c == 0) ? yv[n] : Zm[n*(TT-1) + (c-1)];
        atomicAdd(&red[c], v*v);
    }
    __syncthreads();
    if (tid < TT) atomicAdd(&ssq[tid], red[tid]);
    grid.sync();

    // ---- S2: build r0 = b_norm, rhs norms ----
    for (int e = b*NTHR + tid; e < NTOT; e += NBLK*NTHR) {
        int c = e >> 12, n = e & (NN-1);
        float sc = ssq[c];
        float scale, rh;
        if (c == 0) {
            rh = sqrtf(sc); if (rh < 1e-10f) rh = 1.f;
            scale = 1.f/rh;
        } else {
            float zn = sqrtf(sc);
            float bn = zn/(zn + 1e-10f);
            rh = (bn < 1e-10f) ? 1.f : bn;
            scale = 1.f/((zn + 1e-10f)*rh);
        }
        float raw = (c == 0) ? yv[n] : Zm[n*(TT-1) + (c-1)];
        r_[e] = raw*scale;
        if (n == 0) rhs[c] = rh;
    }
    grid.sync();

    const int row0 = rb*RPB + w*4;
    const float* Kb = Km + (size_t)row0*NN + kb*KSL;
    float* wpo = (kb == 0) ? wp0 : wp1;

    for (int it = 0; it < niters; ++it) {
        // ================= Phase G: w = K r (partials) + gamma/delta reduce =================
        if (tid < TT) { red[tid] = 0.f; gred[tid] = 0.f; }
        // stage r-slice once, [c][k], consecutive-lane b128 writes
        for (int v = tid; v < TT*(KSL/4); v += NTHR) {
            int c = v >> 9, kq = (v & 511) << 2;
            float4 f = *(const float4*)(r_ + c*NN + kb*KSL + kq);
            *(float4*)(rl + c*KSL + kq) = f;
        }
        __syncthreads();

        float acc[4][TT];
        #pragma unroll
        for (int rr = 0; rr < 4; ++rr)
            #pragma unroll
            for (int c = 0; c < TT; ++c) acc[rr][c] = 0.f;

        float4 kv[4], kvn[4];
        #pragma unroll
        for (int rr = 0; rr < 4; ++rr)
            kv[rr] = *(const float4*)(Kb + rr*NN + 4*lane);

        for (int ch = 0; ch < KSL/256; ++ch) {
            if (ch + 1 < KSL/256) {
                #pragma unroll
                for (int rr = 0; rr < 4; ++rr)
                    kvn[rr] = *(const float4*)(Kb + rr*NN + (ch+1)*256 + 4*lane);
            }
            const float* rlc = rl + ch*256 + 4*lane;
            #pragma unroll
            for (int c = 0; c < TT; ++c) {
                float4 rv = *(const float4*)(rlc + c*KSL);   // conflict-free b128
                #pragma unroll
                for (int rr = 0; rr < 4; ++rr)
                    acc[rr][c] += kv[rr].x*rv.x + kv[rr].y*rv.y + kv[rr].z*rv.z + kv[rr].w*rv.w;
            }
            #pragma unroll
            for (int rr = 0; rr < 4; ++rr) kv[rr] = kvn[rr];
        }

        // 64-lane butterfly reduce over k-split
        #pragma unroll
        for (int rr = 0; rr < 4; ++rr)
            #pragma unroll
            for (int c = 0; c < TT; ++c) {
                float v = acc[rr][c];
                v += __shfl_xor(v, 1, 64);
                v += __shfl_xor(v, 2, 64);
                v += __shfl_xor(v, 4, 64);
                v += __shfl_xor(v, 8, 64);
                v += __shfl_xor(v, 16, 64);
                v += __shfl_xor(v, 32, 64);
                acc[rr][c] = v;
            }

        // epilogue: write wpart, accumulate per-column gamma/delta partials
        if (lane < TT) {
            float dpart = 0.f, gpart = 0.f;
            #pragma unroll
            for (int rr = 0; rr < 4; ++rr) {
                int row = row0 + rr;
                float v = acc[rr][lane];
                wpo[lane*NN + row] = v;
                float rv = r_[lane*NN + row];
                dpart += rv*v;
                gpart += rv*rv;
            }
            atomicAdd(&red[lane], dpart);
            if (kb == 0) atomicAdd(&gred[lane], gpart);
        }
        __syncthreads();
        if (tid < TT) {
            atomicAdd(&del[it*TT + tid], red[tid]);
            if (kb == 0) atomicAdd(&gam[it*TT + tid], gred[tid]);
        }
        grid.sync();

        // ================= Phase U: scalars + element-wise updates =================
        if (tid < TT) {
            float g = gam[it*TT + tid];
            float d = del[it*TT + tid] + sigma2*g;        // delta = r^T(K+s2 I)r
            float beta = 0.f;
            if (it > 0) {
                float gp = gam[(it-1)*TT + tid];
                beta = (fabsf(gp) < 1e-30f) ? 0.f : g/gp;
            }
            float ap = aprev[tid];
            float D  = d - ((fabsf(ap) < 1e-30f) ? 0.f : beta*g/ap);
            float alpha = (fabsf(D) < 1e-30f) ? 0.f : g/D;
            al_lds[tid] = alpha; be_lds[tid] = beta; aprev[tid] = alpha;
        }
        __syncthreads();
        {
            int e = b*NTHR + tid;        // 131072 threads cover NTOT
            if (e < NTOT) {
                int c = e >> 12, n = e & (NN-1);
                float alpha = al_lds[c], beta = be_lds[c];
                float rv = r_[e];
                float wv = wp0[e] + wp1[e] + sigma2*rv;   // full w = A r
                float pv = rv + beta*p_[e];
                float sv = wv + beta*s_[e];
                float xv = x_[e] + alpha*pv;
                float rn = rv - alpha*sv;
                p_[e] = pv; s_[e] = sv; x_[e] = xv; r_[e] = rn;
                if (it == niters - 1) out[n*TT + c] = xv*rhs[c];
            }
        }
        grid.sync();
    }
}

extern "C" void kernel_launch(void* const* d_in, const int* in_sizes, int n_in,
                              void* d_out, int out_size, void* d_ws, size_t ws_size,
                              hipStream_t stream) {
    const float* Km    = (const float*)d_in[0];
    const float* yv    = (const float*)d_in[1];
    const float* Zm    = (const float*)d_in[2];
    const float* noise = (const float*)d_in[3];
    const int*   iters = (const int*)d_in[4];
    float* out = (float*)d_out;
    float* ws  = (float*)d_ws;

    void* args[] = { &Km, &yv, &Zm, &noise, &iters, &out, &ws };
    hipLaunchCooperativeKernel((void*)gp_cg_kernel, dim3(NBLK), dim3(NTHR),
                               args, 0, stream);
}